// Round 1
// baseline (20.337 us; speedup 1.0000x reference)
//
#include <hip/hip_runtime.h>
#include <math.h>

#define NLOC 21504
#define N3 16384
#define N4 4096
#define N5 1024
#define CHUNKS (NLOC / 256)   // 84 chunks of 256 locations per batch

__global__ __launch_bounds__(256) void fcos_assign(
    const float* __restrict__ loc3,
    const float* __restrict__ loc4,
    const float* __restrict__ loc5,
    const float* __restrict__ gt,      // (16, 64, 5)
    const float* __restrict__ pred3,   // (16, 16384, 4)
    const float* __restrict__ pred4,   // (16, 4096, 4)
    const float* __restrict__ pred5,   // (16, 1024, 4)
    float* __restrict__ out)           // (16, 21504, 14)
{
    __shared__ float sgt[64 * 5];   // gt boxes for this batch
    __shared__ float sq[64];        // 1e8 - area, precomputed exactly (no FMA)

    const int tid   = threadIdx.x;
    const int b     = blockIdx.x / CHUNKS;
    const int chunk = blockIdx.x % CHUNKS;

    // ---- stage gt[b] (320 floats) into LDS ----
    const float* g = gt + (size_t)b * 320;
    sgt[tid] = g[tid];                       // tid in [0,256)
    if (tid < 64) sgt[tid + 256] = g[tid + 256];
    __syncthreads();

    if (tid < 64) {
        const float x0 = sgt[tid * 5 + 0];
        const float y0 = sgt[tid * 5 + 1];
        const float x1 = sgt[tid * 5 + 2];
        const float y1 = sgt[tid * 5 + 3];
        // Exactly match JAX: area = (x1-x0)*(y1-y0); mm = 1e8 - area.
        // Use _rn intrinsics so -ffp-contract can't fuse and perturb argmax ties.
        const float area = __fmul_rn(__fsub_rn(x1, x0), __fsub_rn(y1, y0));
        sq[tid] = __fsub_rn(1.0e8f, area);
    }
    __syncthreads();

    // ---- per-thread location (block-uniform level) ----
    const int i = chunk * 256 + tid;         // global location index in [0, 21504)
    float cx, cy, stride, lower, upper;
    const float* pred;
    if (i < N3) {
        const int il = i;
        const float2 c = *(const float2*)(loc3 + 2 * il);
        cx = c.x; cy = c.y;
        stride = 8.0f; lower = 0.0f; upper = 64.0f;
        pred = pred3 + ((size_t)b * N3 + il) * 4;
    } else if (i < N3 + N4) {
        const int il = i - N3;
        const float2 c = *(const float2*)(loc4 + 2 * il);
        cx = c.x; cy = c.y;
        stride = 16.0f; lower = 64.0f; upper = 128.0f;
        pred = pred4 + ((size_t)b * N4 + il) * 4;
    } else {
        const int il = i - N3 - N4;
        const float2 c = *(const float2*)(loc5 + 2 * il);
        cx = c.x; cy = c.y;
        stride = 32.0f; lower = 128.0f; upper = INFINITY;
        pred = pred5 + ((size_t)b * N5 + il) * 4;
    }

    // ---- match loop over 64 gt boxes (first-max-wins == jnp.argmax) ----
    float best = 0.0f;
    int   bi   = -1;
    #pragma unroll 8
    for (int j = 0; j < 64; ++j) {
        const float x0 = sgt[j * 5 + 0];
        const float y0 = sgt[j * 5 + 1];
        const float x1 = sgt[j * 5 + 2];
        const float y1 = sgt[j * 5 + 3];
        const float dl = cx - x0;
        const float dt = cy - y0;
        const float dr = x1 - cx;
        const float db = y1 - cy;
        const float mn = fminf(fminf(dl, dt), fminf(dr, db));
        const float mx = fmaxf(fmaxf(dl, dt), fmaxf(dr, db));
        const bool match = (mn > 0.0f) && (mx > lower) && (mx < upper);
        const float mm = match ? sq[j] : 0.0f;
        if (mm > best) { best = mm; bi = j; }   // strict > : first occurrence wins
    }
    // quality < 1e-5 -> background (matched mm is always ~1e8, so bi<0 iff no match)

    float m0, m1, m2, m3, m4;
    if (bi < 0) {
        m0 = m1 = m2 = m3 = m4 = -1.0f;
    } else {
        m0 = sgt[bi * 5 + 0];
        m1 = sgt[bi * 5 + 1];
        m2 = sgt[bi * 5 + 2];
        m3 = sgt[bi * 5 + 3];
        m4 = sgt[bi * 5 + 4];
    }

    // ---- targets + centerness ----
    const bool bg = (m4 == -1.0f);
    float t0, t1, t2, t3, ctr;
    if (bg) {
        t0 = t1 = t2 = t3 = -1.0f;
        ctr = -1.0f;
    } else {
        t0 = (cx - m0) / stride;   // exact: stride is a power of two
        t1 = (cy - m1) / stride;
        t2 = (m2 - cx) / stride;
        t3 = (m3 - cy) / stride;
        const float num = fminf(t0, t2) * fminf(t1, t3);
        const float den = fmaxf(t0, t2) * fmaxf(t1, t3);
        ctr = sqrtf(num / den);
    }

    // ---- decode predictions ----
    const float4 p = *(const float4*)pred;
    const float d0 = cx - fmaxf(p.x, 0.0f) * stride;
    const float d1 = cy - fmaxf(p.y, 0.0f) * stride;
    const float d2 = cx + fmaxf(p.z, 0.0f) * stride;
    const float d3 = cy + fmaxf(p.w, 0.0f) * stride;

    // ---- write 14 channels ----
    float* o = out + ((size_t)b * NLOC + i) * 14;
    o[0]  = d0; o[1]  = d1; o[2]  = d2; o[3]  = d3;
    o[4]  = m0; o[5]  = m1; o[6]  = m2; o[7]  = m3; o[8] = m4;
    o[9]  = t0; o[10] = t1; o[11] = t2; o[12] = t3;
    o[13] = ctr;
}

extern "C" void kernel_launch(void* const* d_in, const int* in_sizes, int n_in,
                              void* d_out, int out_size, void* d_ws, size_t ws_size,
                              hipStream_t stream) {
    const float* loc3 = (const float*)d_in[0];
    const float* loc4 = (const float*)d_in[1];
    const float* loc5 = (const float*)d_in[2];
    const float* gt   = (const float*)d_in[3];
    const float* p3   = (const float*)d_in[4];
    const float* p4   = (const float*)d_in[5];
    const float* p5   = (const float*)d_in[6];
    float* out = (float*)d_out;

    dim3 grid(16 * CHUNKS);   // 1344 blocks, each: one batch, 256 locations
    dim3 block(256);
    hipLaunchKernelGGL(fcos_assign, grid, block, 0, stream,
                       loc3, loc4, loc5, gt, p3, p4, p5, out);
}

// Round 2
// 17.717 us; speedup vs baseline: 1.1479x; 1.1479x over previous
//
#include <hip/hip_runtime.h>
#include <math.h>

#define NLOC 21504
#define N3 16384
#define N4 4096
#define N5 1024
#define CHUNKS (NLOC / 256)   // 84 chunks of 256 locations per batch

__global__ __launch_bounds__(256) void fcos_assign(
    const float* __restrict__ loc3,
    const float* __restrict__ loc4,
    const float* __restrict__ loc5,
    const float* __restrict__ gt,      // (16, 64, 5)
    const float* __restrict__ pred3,   // (16, 16384, 4)
    const float* __restrict__ pred4,   // (16, 4096, 4)
    const float* __restrict__ pred5,   // (16, 1024, 4)
    float* __restrict__ out)           // (16, 21504, 14)
{
    // gt boxes padded to 8 floats: [x0,y0,x1,y1,cls,q,-,-]; q = 1e8 - area
    __shared__ float sbox[64][8];        // 2 KiB
    __shared__ float sout[256 * 14];     // 14 KiB staging for coalesced stores

    const int tid   = threadIdx.x;
    const int b     = blockIdx.x / CHUNKS;
    const int chunk = blockIdx.x % CHUNKS;

    // ---- stage gt[b] into padded LDS rows, precompute quality ----
    if (tid < 64) {
        const float* g = gt + (size_t)b * 320 + tid * 5;
        const float x0 = g[0], y0 = g[1], x1 = g[2], y1 = g[3], cl = g[4];
        sbox[tid][0] = x0; sbox[tid][1] = y0;
        sbox[tid][2] = x1; sbox[tid][3] = y1;
        sbox[tid][4] = cl;
        // Exactly match JAX: q = 1e8 - (x1-x0)*(y1-y0), no FMA contraction.
        sbox[tid][5] = __fsub_rn(1.0e8f,
                        __fmul_rn(__fsub_rn(x1, x0), __fsub_rn(y1, y0)));
    }
    __syncthreads();

    // ---- per-thread location (block-uniform level) ----
    const int i = chunk * 256 + tid;     // global location index in [0, 21504)
    float cx, cy, stride, lower, upper;
    const float* pred;
    if (i < N3) {
        const int il = i;
        const float2 c = *(const float2*)(loc3 + 2 * il);
        cx = c.x; cy = c.y;
        stride = 8.0f; lower = 0.0f; upper = 64.0f;
        pred = pred3 + ((size_t)b * N3 + il) * 4;
    } else if (i < N3 + N4) {
        const int il = i - N3;
        const float2 c = *(const float2*)(loc4 + 2 * il);
        cx = c.x; cy = c.y;
        stride = 16.0f; lower = 64.0f; upper = 128.0f;
        pred = pred4 + ((size_t)b * N4 + il) * 4;
    } else {
        const int il = i - N3 - N4;
        const float2 c = *(const float2*)(loc5 + 2 * il);
        cx = c.x; cy = c.y;
        stride = 32.0f; lower = 128.0f; upper = INFINITY;
        pred = pred5 + ((size_t)b * N5 + il) * 4;
    }

    // ---- match loop over 64 gt boxes (first-max-wins == jnp.argmax) ----
    // mm = match ? q : 0; update iff mm > best  <=>  match && (q > best)
    // (matched q >= 9.9e7 > 0 always; best starts at 0)
    float best = 0.0f;
    int   bi   = -1;
    #pragma unroll 8
    for (int j = 0; j < 64; ++j) {
        const float4 bx = *(const float4*)&sbox[j][0];   // one ds_read_b128
        const float  q  = sbox[j][5];
        const float dl = cx - bx.x;
        const float dt = cy - bx.y;
        const float dr = bx.z - cx;
        const float db = bx.w - cy;
        const float mn = fminf(fminf(dl, dt), fminf(dr, db));
        const float mx = fmaxf(fmaxf(dl, dt), fmaxf(dr, db));
        const bool upd = (mn > 0.0f) && (mx > lower) && (mx < upper) && (q > best);
        best = upd ? q : best;
        bi   = upd ? j : bi;
    }

    float m0, m1, m2, m3, m4;
    if (bi < 0) {
        m0 = m1 = m2 = m3 = m4 = -1.0f;
    } else {
        const float4 bb = *(const float4*)&sbox[bi][0];
        m0 = bb.x; m1 = bb.y; m2 = bb.z; m3 = bb.w;
        m4 = sbox[bi][4];
    }

    // ---- targets + centerness ----
    const bool bg = (m4 == -1.0f);
    float t0, t1, t2, t3, ctr;
    if (bg) {
        t0 = t1 = t2 = t3 = -1.0f;
        ctr = -1.0f;
    } else {
        t0 = (cx - m0) / stride;   // exact: stride is a power of two
        t1 = (cy - m1) / stride;
        t2 = (m2 - cx) / stride;
        t3 = (m3 - cy) / stride;
        const float num = fminf(t0, t2) * fminf(t1, t3);
        const float den = fmaxf(t0, t2) * fmaxf(t1, t3);
        ctr = sqrtf(num / den);
    }

    // ---- decode predictions ----
    const float4 p = *(const float4*)pred;
    const float d0 = cx - fmaxf(p.x, 0.0f) * stride;
    const float d1 = cy - fmaxf(p.y, 0.0f) * stride;
    const float d2 = cx + fmaxf(p.z, 0.0f) * stride;
    const float d3 = cy + fmaxf(p.w, 0.0f) * stride;

    // ---- stage 14 channels in LDS, then coalesced float4 stores ----
    float* so = sout + tid * 14;
    so[0]  = d0; so[1]  = d1; so[2]  = d2; so[3]  = d3;
    so[4]  = m0; so[5]  = m1; so[6]  = m2; so[7]  = m3; so[8] = m4;
    so[9]  = t0; so[10] = t1; so[11] = t2; so[12] = t3;
    so[13] = ctr;
    __syncthreads();

    // 256*14 floats = 896 float4 per block, contiguous in out
    float4* ob = (float4*)(out + ((size_t)b * NLOC + chunk * 256) * 14);
    const float4* sv = (const float4*)sout;
    #pragma unroll
    for (int k = 0; k < 4; ++k) {
        const int idx = k * 256 + tid;
        if (idx < 896) ob[idx] = sv[idx];
    }
}

extern "C" void kernel_launch(void* const* d_in, const int* in_sizes, int n_in,
                              void* d_out, int out_size, void* d_ws, size_t ws_size,
                              hipStream_t stream) {
    const float* loc3 = (const float*)d_in[0];
    const float* loc4 = (const float*)d_in[1];
    const float* loc5 = (const float*)d_in[2];
    const float* gt   = (const float*)d_in[3];
    const float* p3   = (const float*)d_in[4];
    const float* p4   = (const float*)d_in[5];
    const float* p5   = (const float*)d_in[6];
    float* out = (float*)d_out;

    dim3 grid(16 * CHUNKS);   // 1344 blocks, each: one batch, 256 locations
    dim3 block(256);
    hipLaunchKernelGGL(fcos_assign, grid, block, 0, stream,
                       loc3, loc4, loc5, gt, p3, p4, p5, out);
}

// Round 3
// 11.618 us; speedup vs baseline: 1.7505x; 1.5250x over previous
//
#include <hip/hip_runtime.h>
#include <math.h>

#define NLOC 21504
#define N3 16384
#define N4 4096
#define N5 1024
#define CHUNKS (NLOC / 256)   // 84 chunks of 256 locations per batch
// p3 chunks 0..63 (2 rows of 128), p4 chunks 64..79 (4 rows of 64), p5 80..83 (8 rows of 32)

__global__ __launch_bounds__(256) void fcos_assign(
    const float* __restrict__ gt,      // (16, 64, 5)
    const float* __restrict__ pred3,   // (16, 16384, 4)
    const float* __restrict__ pred4,   // (16, 4096, 4)
    const float* __restrict__ pred5,   // (16, 1024, 4)
    float* __restrict__ out)           // (16, 21504, 14)
{
    // candidate boxes (order-preserving compaction): [x0,y0,x1,y1,cls,q,-,-]
    __shared__ float scand[64][8];       // 2 KiB
    __shared__ float sout[256 * 14];     // 14 KiB staging for coalesced stores
    __shared__ int   scnt;

    const int tid   = threadIdx.x;
    const int b     = blockIdx.x / CHUNKS;
    const int chunk = blockIdx.x % CHUNKS;

    // ---- per-thread location, computed arithmetically (bit-exact vs _grid:
    //      (col+0.5)*stride with stride=2^k is exact f32) ----
    const int i = chunk * 256 + tid;     // global location index in [0, 21504)
    float cx, cy, stride, lower, upper, cy_min, cy_max;
    const float* pred;
    if (i < N3) {
        const int il  = i;
        const int col = il & 127, row = il >> 7;
        cx = (col + 0.5f) * 8.0f;  cy = (row + 0.5f) * 8.0f;
        stride = 8.0f; lower = 0.0f; upper = 64.0f;
        const int r0 = chunk * 2;                       // 2 rows per chunk
        cy_min = (r0 + 0.5f) * 8.0f;  cy_max = (r0 + 1.5f) * 8.0f;
        pred = pred3 + ((size_t)b * N3 + il) * 4;
    } else if (i < N3 + N4) {
        const int il  = i - N3;
        const int col = il & 63, row = il >> 6;
        cx = (col + 0.5f) * 16.0f;  cy = (row + 0.5f) * 16.0f;
        stride = 16.0f; lower = 64.0f; upper = 128.0f;
        const int r0 = (chunk - 64) * 4;                // 4 rows per chunk
        cy_min = (r0 + 0.5f) * 16.0f;  cy_max = (r0 + 3.5f) * 16.0f;
        pred = pred4 + ((size_t)b * N4 + il) * 4;
    } else {
        const int il  = i - N3 - N4;
        const int col = il & 31, row = il >> 5;
        cx = (col + 0.5f) * 32.0f;  cy = (row + 0.5f) * 32.0f;
        stride = 32.0f; lower = 128.0f; upper = INFINITY;
        const int r0 = (chunk - 80) * 8;                // 8 rows per chunk
        cy_min = (r0 + 0.5f) * 32.0f;  cy_max = (r0 + 7.5f) * 32.0f;
        pred = pred5 + ((size_t)b * N5 + il) * 4;
    }

    // ---- wave-0 candidate filter over the 64 gt boxes ----
    // A box can match some location in this block only if its feasible-y
    // interval (max(y0,y1-upper), min(y1,y0+upper)) intersects [cy_min,cy_max]
    // and its feasible-x interval is nonempty. Pure necessary conditions with
    // exact float compares => conservative, never drops a matchable box.
    bool keep = false;
    float bx0 = 0, by0 = 0, bx1 = 0, by1 = 0, bcl = 0;
    if (tid < 64) {
        const float* g = gt + (size_t)b * 320 + tid * 5;
        bx0 = g[0]; by0 = g[1]; bx1 = g[2]; by1 = g[3]; bcl = g[4];
        const float ylo = fmaxf(by0, by1 - upper);
        const float yhi = fminf(by1, by0 + upper);
        const float xlo = fmaxf(bx0, bx1 - upper);
        const float xhi = fminf(bx1, bx0 + upper);
        keep = (ylo < cy_max) && (yhi > cy_min) && (xlo < xhi);
    }
    const unsigned long long m = __ballot(keep);   // wave 0's mask of kept boxes
    if (tid < 64) {
        if (keep) {
            // order-preserving compaction => argmax first-max-wins preserved
            const int pos = __popcll(m & ((1ull << tid) - 1ull));
            scand[pos][0] = bx0; scand[pos][1] = by0;
            scand[pos][2] = bx1; scand[pos][3] = by1;
            scand[pos][4] = bcl;
            // Exactly match JAX: q = 1e8 - (x1-x0)*(y1-y0), no FMA contraction.
            scand[pos][5] = __fsub_rn(1.0e8f,
                             __fmul_rn(__fsub_rn(bx1, bx0), __fsub_rn(by1, by0)));
        }
        if (tid == 0) scnt = (int)__popcll(m);
    }
    __syncthreads();
    const int cnt = scnt;

    // ---- match loop over candidates (first-max-wins == jnp.argmax) ----
    float best = 0.0f;
    int   bi   = -1;
    for (int j = 0; j < cnt; ++j) {
        const float4 bx = *(const float4*)&scand[j][0];   // one ds_read_b128
        const float  q  = scand[j][5];
        const float dl = cx - bx.x;
        const float dt = cy - bx.y;
        const float dr = bx.z - cx;
        const float db = bx.w - cy;
        const float mn = fminf(fminf(dl, dt), fminf(dr, db));
        const float mx = fmaxf(fmaxf(dl, dt), fmaxf(dr, db));
        const bool upd = (mn > 0.0f) && (mx > lower) && (mx < upper) && (q > best);
        best = upd ? q : best;
        bi   = upd ? j : bi;
    }

    float m0, m1, m2, m3, m4;
    if (bi < 0) {
        m0 = m1 = m2 = m3 = m4 = -1.0f;
    } else {
        const float4 bb = *(const float4*)&scand[bi][0];
        m0 = bb.x; m1 = bb.y; m2 = bb.z; m3 = bb.w;
        m4 = scand[bi][4];
    }

    // ---- targets + centerness ----
    const bool bg = (m4 == -1.0f);
    float t0, t1, t2, t3, ctr;
    if (bg) {
        t0 = t1 = t2 = t3 = -1.0f;
        ctr = -1.0f;
    } else {
        t0 = (cx - m0) / stride;   // exact: stride is a power of two
        t1 = (cy - m1) / stride;
        t2 = (m2 - cx) / stride;
        t3 = (m3 - cy) / stride;
        const float num = fminf(t0, t2) * fminf(t1, t3);
        const float den = fmaxf(t0, t2) * fmaxf(t1, t3);
        ctr = sqrtf(num / den);
    }

    // ---- decode predictions ----
    const float4 p = *(const float4*)pred;
    const float d0 = cx - fmaxf(p.x, 0.0f) * stride;
    const float d1 = cy - fmaxf(p.y, 0.0f) * stride;
    const float d2 = cx + fmaxf(p.z, 0.0f) * stride;
    const float d3 = cy + fmaxf(p.w, 0.0f) * stride;

    // ---- stage 14 channels in LDS, then coalesced float4 stores ----
    float* so = sout + tid * 14;
    so[0]  = d0; so[1]  = d1; so[2]  = d2; so[3]  = d3;
    so[4]  = m0; so[5]  = m1; so[6]  = m2; so[7]  = m3; so[8] = m4;
    so[9]  = t0; so[10] = t1; so[11] = t2; so[12] = t3;
    so[13] = ctr;
    __syncthreads();

    // 256*14 floats = 896 float4 per block, contiguous in out
    float4* ob = (float4*)(out + ((size_t)b * NLOC + chunk * 256) * 14);
    const float4* sv = (const float4*)sout;
    #pragma unroll
    for (int k = 0; k < 4; ++k) {
        const int idx = k * 256 + tid;
        if (idx < 896) ob[idx] = sv[idx];
    }
}

extern "C" void kernel_launch(void* const* d_in, const int* in_sizes, int n_in,
                              void* d_out, int out_size, void* d_ws, size_t ws_size,
                              hipStream_t stream) {
    const float* gt = (const float*)d_in[3];
    const float* p3 = (const float*)d_in[4];
    const float* p4 = (const float*)d_in[5];
    const float* p5 = (const float*)d_in[6];
    float* out = (float*)d_out;

    dim3 grid(16 * CHUNKS);   // 1344 blocks, each: one batch, 256 locations
    dim3 block(256);
    hipLaunchKernelGGL(fcos_assign, grid, block, 0, stream,
                       gt, p3, p4, p5, out);
}

// Round 4
// 11.188 us; speedup vs baseline: 1.8178x; 1.0384x over previous
//
#include <hip/hip_runtime.h>
#include <math.h>

#define NLOC 21504
#define N3 16384
#define N4 4096
#define N5 1024
#define CHUNKS 84   // 84 chunks of 256 locations per batch
// p3: chunks 0..63  (2 rows x 128 cols), wave = 1 row x 64 cols
// p4: chunks 64..79 (4 rows x 64 cols),  wave = 1 row x 64 cols
// p5: chunks 80..83 (8 rows x 32 cols),  wave = 2 rows x 32 cols

__global__ __launch_bounds__(256) void fcos_assign(
    const float* __restrict__ gt,      // (16, 64, 5)
    const float* __restrict__ pred3,   // (16, 16384, 4)
    const float* __restrict__ pred4,   // (16, 4096, 4)
    const float* __restrict__ pred5,   // (16, 1024, 4)
    float* __restrict__ out)           // (16, 21504, 14)
{
    // Wave-private candidate lists and output staging: NO __syncthreads anywhere.
    __shared__ float scand[4][64][8];   // 8 KiB  [x0,y0,x1,y1,cls,q,-,-]
    __shared__ float sout[4][896];      // 14 KiB (64 locations x 14 ch per wave)

    const int tid   = threadIdx.x;
    const int lane  = tid & 63;
    const int w     = tid >> 6;
    const int b     = blockIdx.x / CHUNKS;
    const int chunk = blockIdx.x % CHUNKS;

    // ---- per-thread location, computed arithmetically (bit-exact vs _grid:
    //      (col+0.5)*2^k is exact in f32) + wave-uniform level/window params ----
    const int i = chunk * 256 + tid;     // global location index in [0, 21504)
    float cx, cy, stride, lower, upper;
    float cx_min, cx_max, cy_min, cy_max;   // wave's location window
    const float* pred;
    if (i < N3) {
        const int row = chunk * 2 + (w >> 1);
        const int col = (w & 1) * 64 + lane;
        cx = (col + 0.5f) * 8.0f;  cy = (row + 0.5f) * 8.0f;
        stride = 8.0f; lower = 0.0f; upper = 64.0f;
        cy_min = cy_max = cy;                       // 1 row per wave
        cx_min = ((w & 1) * 64 + 0.5f) * 8.0f;
        cx_max = ((w & 1) * 64 + 63.5f) * 8.0f;
        pred = pred3 + ((size_t)b * N3 + i) * 4;
    } else if (i < N3 + N4) {
        const int il  = i - N3;
        const int row = il >> 6;                    // = (chunk-64)*4 + w
        const int col = lane;
        cx = (col + 0.5f) * 16.0f;  cy = (row + 0.5f) * 16.0f;
        stride = 16.0f; lower = 64.0f; upper = 128.0f;
        cy_min = cy_max = cy;                       // 1 row per wave
        cx_min = 8.0f;  cx_max = 1016.0f;           // full width
        pred = pred4 + ((size_t)b * N4 + il) * 4;
    } else {
        const int il  = i - N3 - N4;
        const int row = il >> 5;                    // wave covers rows r0, r0+1
        const int col = lane & 31;
        cx = (col + 0.5f) * 32.0f;  cy = (row + 0.5f) * 32.0f;
        stride = 32.0f; lower = 128.0f; upper = INFINITY;
        const int r0 = (il - lane) >> 5;            // first row of this wave
        cy_min = (r0 + 0.5f) * 32.0f;  cy_max = (r0 + 1.5f) * 32.0f;
        cx_min = 16.0f;  cx_max = 1008.0f;          // full width
        pred = pred5 + ((size_t)b * N5 + il) * 4;
    }

    // ---- prefetch prediction (latency hides under filter + match loop) ----
    const float4 p = *(const float4*)pred;

    // ---- per-wave candidate filter: lane <-> box, ballot-compact ----
    // Necessary conditions only (with 0.25px margin >> any f32 rounding of the
    // reference's direct per-location tests), so no matchable box is dropped.
    // Order-preserving compaction keeps jnp.argmax first-max-wins semantics.
    const float* g = gt + (size_t)b * 320 + lane * 5;
    const float bx0 = g[0], by0 = g[1], bx1 = g[2], by1 = g[3], bcl = g[4];
    const float eps = 0.25f;
    const float ylo = fmaxf(by0, by1 - upper), yhi = fminf(by1, by0 + upper);
    const float xlo = fmaxf(bx0, bx1 - upper), xhi = fminf(bx1, bx0 + upper);
    const bool keep = (ylo < cy_max + eps) && (yhi > cy_min - eps)
                   && (xlo < cx_max + eps) && (xhi > cx_min - eps)
                   && (fmaxf(bx1 - bx0, by1 - by0) > lower - eps);
    const unsigned long long mball = __ballot(keep);
    const int cnt = (int)__popcll(mball);
    if (keep) {
        const int pos = (int)__popcll(mball & ((1ull << lane) - 1ull));
        scand[w][pos][0] = bx0; scand[w][pos][1] = by0;
        scand[w][pos][2] = bx1; scand[w][pos][3] = by1;
        scand[w][pos][4] = bcl;
        // Exactly match JAX: q = 1e8 - (x1-x0)*(y1-y0), no FMA contraction.
        scand[w][pos][5] = __fsub_rn(1.0e8f,
                            __fmul_rn(__fsub_rn(bx1, bx0), __fsub_rn(by1, by0)));
    }
    __builtin_amdgcn_wave_barrier();   // wave-synchronous LDS: pin write->read order

    // ---- match loop over candidates (first-max-wins == jnp.argmax) ----
    float best = 0.0f;
    int   bi   = -1;
    for (int j = 0; j < cnt; ++j) {
        const float4 bx = *(const float4*)&scand[w][j][0];  // broadcast ds_read_b128
        const float  q  = scand[w][j][5];
        const float dl = cx - bx.x;
        const float dt = cy - bx.y;
        const float dr = bx.z - cx;
        const float db = bx.w - cy;
        const float mn = fminf(fminf(dl, dt), fminf(dr, db));
        const float mx = fmaxf(fmaxf(dl, dt), fmaxf(dr, db));
        const bool upd = (mn > 0.0f) && (mx > lower) && (mx < upper) && (q > best);
        best = upd ? q : best;
        bi   = upd ? j : bi;
    }

    float m0, m1, m2, m3, m4;
    if (bi < 0) {
        m0 = m1 = m2 = m3 = m4 = -1.0f;
    } else {
        const float4 bb = *(const float4*)&scand[w][bi][0];
        m0 = bb.x; m1 = bb.y; m2 = bb.z; m3 = bb.w;
        m4 = scand[w][bi][4];
    }

    // ---- targets + centerness ----
    const bool bg = (m4 == -1.0f);
    float t0, t1, t2, t3, ctr;
    if (bg) {
        t0 = t1 = t2 = t3 = -1.0f;
        ctr = -1.0f;
    } else {
        t0 = (cx - m0) / stride;   // exact: stride is a power of two
        t1 = (cy - m1) / stride;
        t2 = (m2 - cx) / stride;
        t3 = (m3 - cy) / stride;
        const float num = fminf(t0, t2) * fminf(t1, t3);
        const float den = fmaxf(t0, t2) * fmaxf(t1, t3);
        ctr = sqrtf(num / den);
    }

    // ---- decode predictions ----
    const float d0 = cx - fmaxf(p.x, 0.0f) * stride;
    const float d1 = cy - fmaxf(p.y, 0.0f) * stride;
    const float d2 = cx + fmaxf(p.z, 0.0f) * stride;
    const float d3 = cy + fmaxf(p.w, 0.0f) * stride;

    // ---- wave-private staging, then coalesced float4 stores (no barrier) ----
    float2* so2 = (float2*)&sout[w][lane * 14];
    so2[0] = make_float2(d0, d1);
    so2[1] = make_float2(d2, d3);
    so2[2] = make_float2(m0, m1);
    so2[3] = make_float2(m2, m3);
    so2[4] = make_float2(m4, t0);
    so2[5] = make_float2(t1, t2);
    so2[6] = make_float2(t3, ctr);
    __builtin_amdgcn_wave_barrier();

    // 64 locations x 14 ch = 896 floats = 224 float4 per wave, contiguous
    float4* ob = (float4*)(out + (((size_t)b * NLOC) + (size_t)chunk * 256 + w * 64) * 14);
    const float4* sv = (const float4*)&sout[w][0];
    ob[lane]       = sv[lane];
    ob[64 + lane]  = sv[64 + lane];
    ob[128 + lane] = sv[128 + lane];
    if (lane < 32) ob[192 + lane] = sv[192 + lane];
}

extern "C" void kernel_launch(void* const* d_in, const int* in_sizes, int n_in,
                              void* d_out, int out_size, void* d_ws, size_t ws_size,
                              hipStream_t stream) {
    const float* gt = (const float*)d_in[3];
    const float* p3 = (const float*)d_in[4];
    const float* p4 = (const float*)d_in[5];
    const float* p5 = (const float*)d_in[6];
    float* out = (float*)d_out;

    dim3 grid(16 * CHUNKS);   // 1344 blocks, each: one batch, 256 locations
    dim3 block(256);
    hipLaunchKernelGGL(fcos_assign, grid, block, 0, stream,
                       gt, p3, p4, p5, out);
}